// Round 8
// baseline (511.721 us; speedup 1.0000x reference)
//
#include <hip/hip_runtime.h>
#include <math.h>

// Problem constants (reference: VOCAB=10000, HID=256, B=64, T=64)
#define VOCABN 10000
#define HIDN   256
#define GATES  1024   // 4*HID
#define BN     64
#define TN     64
#define BT     4096   // B*T
#define NCT    625    // vocab col-tiles of 16 (10000 = 625*16 exactly)

typedef unsigned int       u32;
typedef unsigned short     u16;
typedef unsigned long long u64;
typedef float v4f __attribute__((ext_vector_type(4)));
typedef short v8s __attribute__((ext_vector_type(8)));

#define SENT 0xFFFFFFFFFFFFFFFFull   // 4x bf16 -NaN: never a legal h pack

__device__ __forceinline__ float bf2f(u16 u) {
    return __uint_as_float(((u32)u) << 16);
}
__device__ __forceinline__ u16 f2bf(float f) {          // round-to-nearest-even
    u32 u = __float_as_uint(f);
    u += 0x7FFFu + ((u >> 16) & 1u);
    return (u16)(u >> 16);
}
__device__ __forceinline__ float fast_sigmoid(float x) {
    return 1.0f / (1.0f + __expf(-x));
}
__device__ __forceinline__ float fast_tanh(float x) {
    float e = __expf(-2.0f * fabsf(x));
    float t = (1.0f - e) / (1.0f + e);
    return copysignf(t, x);
}
__device__ __forceinline__ u64 llc_load(const u64* p) {
    return __hip_atomic_load(p, __ATOMIC_RELAXED, __HIP_MEMORY_SCOPE_AGENT);
}
__device__ __forceinline__ void llc_store(u64* p, u64 v) {
    __hip_atomic_store(p, v, __ATOMIC_RELAXED, __HIP_MEMORY_SCOPE_AGENT);
}

// ---------------------------------------------------------------------------
// fp32 [HIDN][ncols] tile c -> bf16 MFMA B-fragment layout [c][8 q][64 l][8].
// Fragment (c,q), lane l holds B[k = q*32 + (l>>4)*8 + j][n = c*16 + (l&15)].
// ---------------------------------------------------------------------------
__device__ __forceinline__ void wfrag_dev(
    const float* __restrict__ src, u16* __restrict__ dst, int ncols, int c,
    int t, u16 lt[HIDN][16])
{
    const float* s = src + (size_t)t * ncols + c * 16;
    #pragma unroll
    for (int j4 = 0; j4 < 4; ++j4) {
        float4 v = *(const float4*)(s + j4 * 4);
        lt[t][j4*4+0] = f2bf(v.x);
        lt[t][j4*4+1] = f2bf(v.y);
        lt[t][j4*4+2] = f2bf(v.z);
        lt[t][j4*4+3] = f2bf(v.w);
    }
    __syncthreads();
    #pragma unroll
    for (int h = 0; h < 2; ++h) {
        int f = t + h * 256;             // frag id = q*64 + l
        int q = f >> 6, l = f & 63;
        int m = l & 15, kb = q * 32 + ((l >> 4) & 3) * 8;
        u32 w[4];
        #pragma unroll
        for (int j = 0; j < 4; ++j)
            w[j] = (u32)lt[kb + 2*j][m] | ((u32)lt[kb + 2*j + 1][m] << 16);
        *(uint4*)(dst + (((size_t)c * 8 + q) * 64 + l) * 8) =
            make_uint4(w[0], w[1], w[2], w[3]);
    }
}

// ---------------------------------------------------------------------------
// Prep 1 (753 blocks): all three weight transforms.
//   0..63   : W_lstm x-part  -> Wxf
//   64..127 : W_lstm h-part  -> Whf
//   128..752: W_dense        -> Wf
// ---------------------------------------------------------------------------
__global__ __launch_bounds__(256) void k_prep1(
    const float* __restrict__ W_lstm,
    const float* __restrict__ W_dense,
    u16* __restrict__ Wxf, u16* __restrict__ Whf, u16* __restrict__ Wf)
{
    __shared__ u16 lt[HIDN][16];
    const int bid = blockIdx.x;
    if (bid < 64)
        wfrag_dev(W_lstm, Wxf, GATES, bid, threadIdx.x, lt);
    else if (bid < 128)
        wfrag_dev(W_lstm + (size_t)HIDN * GATES, Whf, GATES, bid - 64,
                  threadIdx.x, lt);
    else
        wfrag_dev(W_dense, Wf, VOCABN, bid - 128, threadIdx.x, lt);
}

// ---------------------------------------------------------------------------
// Prep 2 (256 blocks): gates_x = E[idx] @ W_x + b_lstm -> bf16.
// ---------------------------------------------------------------------------
__global__ __launch_bounds__(256) void k_prep2(
    const int*   __restrict__ idx,   // [BT]
    const float* __restrict__ E,     // [VOCAB][HIDN]
    const u16*   __restrict__ Wxf,   // [64][8][64][8]
    const float* __restrict__ bl,    // [GATES]
    u16*         __restrict__ gxb)   // [BT][GATES] bf16
{
    const int r0   = blockIdx.x * 16;
    const int tid  = threadIdx.x;
    const int w    = tid >> 6, lane = tid & 63;
    const int m    = lane & 15, quad = lane >> 4;

    v8s a[8];
    {
        const float* e = E + (size_t)idx[r0 + m] * HIDN + quad * 8;
        #pragma unroll
        for (int q = 0; q < 8; ++q) {
            float4 x0 = *(const float4*)(e + q * 32);
            float4 x1 = *(const float4*)(e + q * 32 + 4);
            uint4 t4 = make_uint4(
                (u32)f2bf(x0.x) | ((u32)f2bf(x0.y) << 16),
                (u32)f2bf(x0.z) | ((u32)f2bf(x0.w) << 16),
                (u32)f2bf(x1.x) | ((u32)f2bf(x1.y) << 16),
                (u32)f2bf(x1.z) | ((u32)f2bf(x1.w) << 16));
            a[q] = *(v8s*)&t4;
        }
    }
    for (int c = w; c < GATES / 16; c += 4) {
        v4f acc = {0.f, 0.f, 0.f, 0.f};
        #pragma unroll
        for (int q = 0; q < 8; ++q) {
            v8s b = *(const v8s*)(Wxf + (((size_t)c * 8 + q) * 64 + lane) * 8);
            acc = __builtin_amdgcn_mfma_f32_16x16x32_bf16(a[q], b, acc, 0, 0, 0);
        }
        const int col = c * 16 + m;
        const float bv = bl[col];
        #pragma unroll
        for (int r = 0; r < 4; ++r)   // D: col=lane&15, row=quad*4+r (m89/m91)
            gxb[(size_t)(r0 + quad * 4 + r) * GATES + col] = f2bf(acc[r] + bv);
    }
}

// ---------------------------------------------------------------------------
// MEGA kernel, 96 blocks:
//   blocks 0..31 : persistent MFMA LSTM (4 row-groups x 8 unit-slices).
//     W_h slice LDS-resident; h published per step to LLC exchange Hx[t]
//     (sentinel-filled) via relaxed agent u64 stores. Wave 0 ALONE polls the
//     data words (a-frag addresses are wave-invariant) and stages them in
//     LDS; other waves ds_read — 4x less LLC poll traffic than R7.
//     After the end-of-step barrier (publish stores drained), tid0 fires a
//     relaxed agent atomicAdd on flags[t] (32 producers per step).
//   blocks 32..95: dense+softmax, one per timestep t, FULL 64-row batch:
//     tid0 sleep-polls flags[t]==32 (one u32 — no data polling), then the
//     block bulk-loads its 64 rows of Hx[t] (agent loads, LLC-coherent),
//     holds all 4 row-tile a-frag sets in registers, sweeps the vocab once
//     (5.12 MB Wf per block, 64 blocks = half of R7's Wf traffic), captures
//     target logits in-flight, writes final perplexities.
// No deadlock: 96 blocks < 256 CUs -> all resident regardless of order.
// ---------------------------------------------------------------------------
__global__ __launch_bounds__(256, 1) void k_mega(
    const u16*   __restrict__ Whf,   // [64 ct][8][64][8] h-part frags
    const u16*   __restrict__ gxb,   // [BT][GATES] bf16
    u16*                      Hx,    // [64][BN][HIDN] bf16, sentinel-filled
    const u16*   __restrict__ Wf,    // [625][8][64][8]
    const float* __restrict__ bd,    // [VOCAB]
    const int*   __restrict__ tgt,   // [B][T]
    u32*                      flags, // [TN], zeroed per launch
    float*       __restrict__ out)   // [B][T] perplexity
{
    __shared__ union {
        struct {
            uint4 Wl4[8 * 512];          // 64 KB W_h slice (B-frag layout)
            float gl[4][16][33];         // gate exchange (+1 pad)
            u64   ha[64][17];            // staged a-frags (+1 u64 pad)
        } p;                              // recurrence role (~81 KB)
        struct { float Sl[64]; float tlv[64]; int tg[64]; } d;   // dense role
    } sm;

    const int tid  = threadIdx.x;
    const int w    = tid >> 6;
    const int lane = tid & 63;
    const int m    = lane & 15, kq = lane >> 4;

    if (blockIdx.x < 32) {
        // ================= recurrence role =================
        const int rg = blockIdx.x >> 3;    // row group: batch rows rg*16..+15
        const int ns = blockIdx.x & 7;     // unit slice: units ns*32..+31
        const int u0 = ns * 32;

        {   // W_h slice: tiles ct = g*16 + ns*2 + ut (g=0..3, ut=0..1)
            const uint4* src = (const uint4*)Whf;
            #pragma unroll
            for (int i = 0; i < 16; ++i) {
                int e  = tid + i * 256;
                int tl = e >> 9, off = e & 511;
                int ct = (tl >> 1) * 16 + ns * 2 + (tl & 1);
                sm.p.Wl4[e] = src[(size_t)ct * 512 + off];
            }
        }
        for (int e = tid; e < 4 * 16 * 33; e += 256) ((float*)sm.p.gl)[e] = 0.0f;
        __syncthreads();

        const u16* Wl = (const u16*)sm.p.Wl4;
        const int r = tid >> 4, u = tid & 15;
        const int b = rg * 16 + r;
        const u16* gxp = gxb + (size_t)b * TN * GATES + u0 + u;
        const size_t hxw = (size_t)b * HIDN + u0 + u;
        const size_t arow64 = (size_t)(rg * 16 + m) * (HIDN / 4) + kq * 2;

        float cst0 = 0.0f, cst1 = 0.0f;
        float gr[8], gn[8];
        #pragma unroll
        for (int g = 0; g < 4; ++g) {
            gr[g]     = bf2f(gxp[g * 256]);
            gr[g + 4] = bf2f(gxp[g * 256 + 16]);
        }

        for (int t = 0; t < TN; ++t) {
            if (t + 1 < TN) {
                const u16* p = gxp + (size_t)(t + 1) * GATES;
                #pragma unroll
                for (int g = 0; g < 4; ++g) {
                    gn[g]     = bf2f(p[g * 256]);
                    gn[g + 4] = bf2f(p[g * 256 + 16]);
                }
            }

            if (t > 0) {
                if (w == 0) {
                    // wave 0 alone polls h(t-1) at LLC, stages into LDS
                    const u64* hb64 = (const u64*)Hx
                        + (size_t)(t - 1) * (BN * HIDN / 4) + arow64;
                    u64 d0[8], d1[8];
                    bool ok = false;
                    while (!ok) {
                        ok = true;
                        #pragma unroll
                        for (int q = 0; q < 8; ++q) {
                            d0[q] = llc_load(hb64 + q * 8);
                            d1[q] = llc_load(hb64 + q * 8 + 1);
                        }
                        #pragma unroll
                        for (int q = 0; q < 8; ++q)
                            if (d0[q] == SENT || d1[q] == SENT) ok = false;
                    }
                    #pragma unroll
                    for (int q = 0; q < 8; ++q) {
                        sm.p.ha[lane][2 * q]     = d0[q];
                        sm.p.ha[lane][2 * q + 1] = d1[q];
                    }
                }
                __syncthreads();               // (A) staged a-frags ready

                v4f acc0 = {0.f,0.f,0.f,0.f}, acc1 = {0.f,0.f,0.f,0.f};
                #pragma unroll
                for (int q = 0; q < 8; ++q) {
                    v8s av  = *(const v8s*)&sm.p.ha[lane][2 * q];
                    v8s bf0 = *(const v8s*)(Wl + (((w * 2 + 0) * 8 + q) * 64 + lane) * 8);
                    v8s bf1 = *(const v8s*)(Wl + (((w * 2 + 1) * 8 + q) * 64 + lane) * 8);
                    acc0 = __builtin_amdgcn_mfma_f32_16x16x32_bf16(av, bf0, acc0, 0, 0, 0);
                    acc1 = __builtin_amdgcn_mfma_f32_16x16x32_bf16(av, bf1, acc1, 0, 0, 0);
                }
                #pragma unroll
                for (int rr = 0; rr < 4; ++rr) {  // row = kq*4+rr, unit = m
                    sm.p.gl[w][kq * 4 + rr][m]      = acc0[rr];
                    sm.p.gl[w][kq * 4 + rr][16 + m] = acc1[rr];
                }
            }
            __syncthreads();                   // (B) gate exchange ready

            {
                float ai0 = sm.p.gl[0][r][u]      + gr[0];
                float aj0 = sm.p.gl[1][r][u]      + gr[1];
                float af0 = sm.p.gl[2][r][u]      + gr[2];
                float ao0 = sm.p.gl[3][r][u]      + gr[3];
                float ai1 = sm.p.gl[0][r][u + 16] + gr[4];
                float aj1 = sm.p.gl[1][r][u + 16] + gr[5];
                float af1 = sm.p.gl[2][r][u + 16] + gr[6];
                float ao1 = sm.p.gl[3][r][u + 16] + gr[7];

                float ig0 = fast_sigmoid(ai0), fg0 = fast_sigmoid(af0 + 1.0f);
                float og0 = fast_sigmoid(ao0), jt0 = fast_tanh(aj0);
                cst0 = fg0 * cst0 + ig0 * jt0;
                float hn0 = og0 * fast_tanh(cst0);
                float ig1 = fast_sigmoid(ai1), fg1 = fast_sigmoid(af1 + 1.0f);
                float og1 = fast_sigmoid(ao1), jt1 = fast_tanh(aj1);
                cst1 = fg1 * cst1 + ig1 * jt1;
                float hn1 = og1 * fast_tanh(cst1);

                u32 h0 = f2bf(hn0), h1 = f2bf(hn1);
                u32 a1 = __shfl_down(h0, 1), a2 = __shfl_down(h0, 2), a3 = __shfl_down(h0, 3);
                u32 b1 = __shfl_down(h1, 1), b2 = __shfl_down(h1, 2), b3 = __shfl_down(h1, 3);
                if ((tid & 3) == 0) {
                    u64* dst = (u64*)(Hx + (size_t)t * (BN * HIDN) + hxw);
                    u64 pk0 = (u64)(h0 | (a1 << 16)) | ((u64)(a2 | (a3 << 16)) << 32);
                    u64 pk1 = (u64)(h1 | (b1 << 16)) | ((u64)(b2 | (b3 << 16)) << 32);
                    llc_store(dst,     pk0);
                    llc_store(dst + 4, pk1);
                }
            }

            __syncthreads();   // (C) publish stores drained (vmcnt(0) before
                               //     s_barrier per wave) + gl/ha rewrite safe
            if (tid == 0)
                __hip_atomic_fetch_add(&flags[t], 1u, __ATOMIC_RELAXED,
                                       __HIP_MEMORY_SCOPE_AGENT);
            #pragma unroll
            for (int g = 0; g < 8; ++g) gr[g] = gn[g];
        }
        return;
    }

    // ================= dense role =================
    const int tt = blockIdx.x - 32;    // timestep 0..63

    if (tid < 64) {
        sm.d.Sl[tid] = 0.0f;
        sm.d.tg[tid] = tgt[(size_t)tid * TN + tt];
    }
    __syncthreads();

    if (tid == 0) {
        while (__hip_atomic_load(&flags[tt], __ATOMIC_RELAXED,
                                 __HIP_MEMORY_SCOPE_AGENT) < 32u)
            __builtin_amdgcn_s_sleep(16);
    }
    __syncthreads();

    // bulk-load all 64 rows of Hx[tt] into register a-frags (4 row-tiles)
    v8s a[4][8];
    {
        const u64* base = (const u64*)Hx
            + ((size_t)tt * BN + m) * (HIDN / 4) + kq * 2;
        #pragma unroll
        for (int rt = 0; rt < 4; ++rt) {
            const u64* bp = base + (size_t)rt * 16 * (HIDN / 4);
            #pragma unroll
            for (int q = 0; q < 8; ++q) {
                union { u64 d[2]; v8s v; } av;
                av.d[0] = llc_load(bp + q * 8);
                av.d[1] = llc_load(bp + q * 8 + 1);
                a[rt][q] = av.v;
            }
        }
    }

    float s[4][4] = {{0.f,0.f,0.f,0.f},{0.f,0.f,0.f,0.f},
                     {0.f,0.f,0.f,0.f},{0.f,0.f,0.f,0.f}};
    for (int c = w; c < NCT; c += 4) {
        v4f acc[4] = {{0.f,0.f,0.f,0.f},{0.f,0.f,0.f,0.f},
                      {0.f,0.f,0.f,0.f},{0.f,0.f,0.f,0.f}};
        #pragma unroll
        for (int q = 0; q < 8; ++q) {
            v8s bq = *(const v8s*)(Wf + (((size_t)c * 8 + q) * 64 + lane) * 8);
            #pragma unroll
            for (int rt = 0; rt < 4; ++rt)
                acc[rt] = __builtin_amdgcn_mfma_f32_16x16x32_bf16(
                              a[rt][q], bq, acc[rt], 0, 0, 0);
        }
        const int col = c * 16 + m;
        const float bv = bd[col];
        #pragma unroll
        for (int rt = 0; rt < 4; ++rt)
            #pragma unroll
            for (int r = 0; r < 4; ++r) {
                float l = acc[rt][r] + bv;
                int row = rt * 16 + kq * 4 + r;       // batch row 0..63
                if (col == sm.d.tg[row]) sm.d.tlv[row] = l;
                s[rt][r] += __expf(l);
            }
    }
    #pragma unroll
    for (int rt = 0; rt < 4; ++rt)
        #pragma unroll
        for (int r = 0; r < 4; ++r)
            atomicAdd(&sm.d.Sl[rt * 16 + kq * 4 + r], s[rt][r]);
    __syncthreads();
    if (tid < 64)
        out[(size_t)tid * TN + tt] =
            __expf(__logf(sm.d.Sl[tid]) - sm.d.tlv[tid]);
}

// ---------------------------------------------------------------------------
extern "C" void kernel_launch(void* const* d_in, const int* in_sizes, int n_in,
                              void* d_out, int out_size, void* d_ws, size_t ws_size,
                              hipStream_t stream) {
    const int*   input   = (const int*)  d_in[0];   // [B,T]
    const int*   targets = (const int*)  d_in[1];   // [B,T]
    const float* E       = (const float*)d_in[2];   // [VOCAB,HID]
    const float* W_lstm  = (const float*)d_in[3];   // [2H,4H]
    const float* b_lstm  = (const float*)d_in[4];   // [4H]
    const float* W_dense = (const float*)d_in[5];   // [HID,VOCAB]
    const float* b_dense = (const float*)d_in[6];   // [VOCAB]
    float* out = (float*)d_out;                     // [B,T] perplexity

    // Workspace (~16.3 MB; 20 MB proven in earlier rounds):
    //  [0,8M):           gxb bf16 [BT][GATES]
    //  [8M,13.12M):      Wf  bf16 [625][8][64][8]
    //  [13.25M,+512K):   Whf (h-part frags)
    //  [13.75M,+512K):   Wxf (x-part frags)
    //  [14.25M,+2M):     Hx bf16 [64][BN][HIDN] sentinel-initialized
    //  [16.25M,+256B):   flags u32 [64] zero-initialized
    char* ws = (char*)d_ws;
    u16* gxb   = (u16*)ws;
    u16* Wf    = (u16*)(ws + ((size_t)8 << 20));
    u16* Whf   = (u16*)(ws + ((size_t)13 << 20) + ((size_t)256 << 10));
    u16* Wxf   = (u16*)(ws + ((size_t)13 << 20) + ((size_t)768 << 10));
    u16* Hx    = (u16*)(ws + ((size_t)14 << 20) + ((size_t)256 << 10));
    u32* flags = (u32*)(ws + ((size_t)16 << 20) + ((size_t)256 << 10));

    hipMemsetAsync(Hx, 0xFF, (size_t)2 << 20, stream);   // sentinel fill
    hipMemsetAsync(flags, 0, 256, stream);
    k_prep1<<<753,      256, 0, stream>>>(W_lstm, W_dense, Wxf, Whf, Wf);
    k_prep2<<<BT / 16,  256, 0, stream>>>(input, E, Wxf, b_lstm, gxb);
    k_mega <<<96,       256, 0, stream>>>(Whf, gxb, Hx, Wf, b_dense,
                                          targets, flags, out);
}